// Round 4
// baseline (120.785 us; speedup 1.0000x reference)
//
#include <hip/hip_runtime.h>
#include <math.h>

// RepulsionLoss: B=8, N=4096, 3D points, k=4 NN (skip self), H=0.03
// loss = sum_q sum_{4NN} -d * exp(-d / H^2)
//
// Round-4: manual 4-wide load batching (4 global_load_dwordx4 in flight,
// literal offsets off one base pointer), shifted distance |p|^2 - 2 p.q
// (3 fma/pair; |q|^2 added back after merge), branchless INSERT5,
// 16 lanes/query, butterfly merge, deterministic 2-stage reduction.

#define NB     8
#define NPTS   4096
#define INV_H2 1111.1111111111111f   // 1 / (0.03*0.03)
#define BIG    1e30f

// parallel branchless insert of 'e' into sorted ascending d0..d4 (9 min/max)
#define INSERT5(e)                          \
    do {                                    \
        float _m0 = fmaxf(d0, (e));         \
        float _m1 = fmaxf(d1, (e));         \
        float _m2 = fmaxf(d2, (e));         \
        float _m3 = fmaxf(d3, (e));         \
        d0 = fminf(d0, (e));                \
        d1 = fminf(d1, _m0);                \
        d2 = fminf(d2, _m1);                \
        d3 = fminf(d3, _m2);                \
        d4 = fminf(d4, _m3);                \
    } while (0)

// ---------------- prep: (x,y,z) -> (x,y,z,|p|^2) ------------------------------
__global__ __launch_bounds__(256) void prep_kernel(const float* __restrict__ pc,
                                                   float4* __restrict__ pts4) {
    int i = blockIdx.x * 256 + threadIdx.x;
    if (i < NB * NPTS) {
        float x = pc[3 * i + 0];
        float y = pc[3 * i + 1];
        float z = pc[3 * i + 2];
        float n = fmaf(x, x, fmaf(y, y, z * z));
        pts4[i] = make_float4(x, y, z, n);
    }
}

// ---------------- main: 16 lanes/query, 4-batched scan, butterfly merge --------
// block = 256 threads = 4 waves; each wave: 4 queries x 16 scan-lanes.
// grid = NB * 256 = 2048 blocks (16 queries per block).
__global__ __launch_bounds__(256, 8) void knn_kernel(const float4* __restrict__ pts4,
                                                     float* __restrict__ partials) {
    const int tid  = threadIdx.x;
    const int lane = tid & 63;
    const int wid  = tid >> 6;
    const int qg   = lane >> 4;   // query slot within wave: 0..3
    const int s    = lane & 15;   // scan subset: 0..15

    const int b  = blockIdx.x >> 8;                           // 256 blocks per batch
    const int iq = ((blockIdx.x & 255) << 4) + (wid << 2) + qg;

    const float4* __restrict__ base = pts4 + b * NPTS;
    const float4 qp = base[iq];
    const float nqx = -2.0f * qp.x;
    const float nqy = -2.0f * qp.y;
    const float nqz = -2.0f * qp.z;
    const float Cq  = qp.w;       // |q|^2, re-added after merge

    // sorted ascending top-5 of SHIFTED distance |p|^2 - 2 p.q
    // (self == -|q|^2 is the exact minimum -> lands in d0, dropped)
    float d0 = BIG, d1 = BIG, d2 = BIG, d3 = BIG, d4 = BIG;

    // lane s scans j = t*16 + s; 4 candidates per trip, loads batched so the
    // compiler emits 4 back-to-back global_load_dwordx4 with literal offsets.
    const float4* __restrict__ p = base + s;
    for (int t = 0; t < NPTS / 16 / 4; ++t) {
        float4 va = p[0];
        float4 vb = p[16];
        float4 vc = p[32];
        float4 vd = p[48];
        p += 64;

        float a = fmaf(va.x, nqx, va.w);
        float bb = fmaf(vb.x, nqx, vb.w);
        float c = fmaf(vc.x, nqx, vc.w);
        float dpt = fmaf(vd.x, nqx, vd.w);
        a  = fmaf(va.y, nqy, a);
        bb = fmaf(vb.y, nqy, bb);
        c  = fmaf(vc.y, nqy, c);
        dpt= fmaf(vd.y, nqy, dpt);
        a  = fmaf(va.z, nqz, a);
        bb = fmaf(vb.z, nqz, bb);
        c  = fmaf(vc.z, nqz, c);
        dpt= fmaf(vd.z, nqz, dpt);

        INSERT5(a);
        INSERT5(bb);
        INSERT5(c);
        INSERT5(dpt);
    }

    // merge the 16 subsets' sorted top-5 lists (xor butterfly over low 4 bits)
    #pragma unroll
    for (int m = 1; m <= 8; m <<= 1) {
        float e0 = __shfl_xor(d0, m);
        float e1 = __shfl_xor(d1, m);
        float e2 = __shfl_xor(d2, m);
        float e3 = __shfl_xor(d3, m);
        float e4 = __shfl_xor(d4, m);
        INSERT5(e0);
        INSERT5(e1);
        INSERT5(e2);
        INSERT5(e3);
        INSERT5(e4);
    }

    // d0 == self; d1..d4 + Cq are the 4 true NN squared distances.
    float lsum = 0.0f;
    if (s == 0) {
        float e1 = fmaxf(d1 + Cq, 0.0f);
        float e2 = fmaxf(d2 + Cq, 0.0f);
        float e3 = fmaxf(d3 + Cq, 0.0f);
        float e4 = fmaxf(d4 + Cq, 0.0f);
        lsum = e1 * __expf(-e1 * INV_H2)
             + e2 * __expf(-e2 * INV_H2)
             + e3 * __expf(-e3 * INV_H2)
             + e4 * __expf(-e4 * INV_H2);
        lsum = -lsum;
    }

    // wave reduce (lanes with s!=0 hold 0)
    #pragma unroll
    for (int m = 32; m >= 1; m >>= 1) lsum += __shfl_xor(lsum, m);

    __shared__ float wsum[4];
    if (lane == 0) wsum[wid] = lsum;
    __syncthreads();
    if (tid == 0) partials[blockIdx.x] = wsum[0] + wsum[1] + wsum[2] + wsum[3];
}

// ---------------- final reduction of 2048 block partials -----------------------
__global__ __launch_bounds__(256) void reduce_kernel(const float* __restrict__ partials,
                                                     float* __restrict__ out) {
    int tid = threadIdx.x;
    float v = 0.0f;
    #pragma unroll
    for (int i = 0; i < 8; ++i) v += partials[tid + 256 * i];
    #pragma unroll
    for (int m = 32; m >= 1; m >>= 1) v += __shfl_xor(v, m);
    __shared__ float ws[4];
    if ((tid & 63) == 0) ws[tid >> 6] = v;
    __syncthreads();
    if (tid == 0) out[0] = ws[0] + ws[1] + ws[2] + ws[3];
}

extern "C" void kernel_launch(void* const* d_in, const int* in_sizes, int n_in,
                              void* d_out, int out_size, void* d_ws, size_t ws_size,
                              hipStream_t stream) {
    const float* pc = (const float*)d_in[0];
    float* out = (float*)d_out;

    float4* pts4    = (float4*)d_ws;
    float* partials = (float*)((char*)d_ws + (size_t)NB * NPTS * sizeof(float4));

    prep_kernel<<<(NB * NPTS + 255) / 256, 256, 0, stream>>>(pc, pts4);
    knn_kernel<<<NB * 256, 256, 0, stream>>>(pts4, partials);
    reduce_kernel<<<1, 256, 0, stream>>>(partials, out);
}

// Round 5
// 94.423 us; speedup vs baseline: 1.2792x; 1.2792x over previous
//
#include <hip/hip_runtime.h>
#include <math.h>

// RepulsionLoss: B=8, N=4096, 3D points, k=4 NN (skip self), H=0.03
// loss = sum_q sum_{4NN} -d * exp(-d / H^2)
//
// Round-5: register-tiled Q=4 queries per lane (each loaded point feeds 4
// queries -> 4x arithmetic intensity per load, fixing L1/TA oversubscription),
// med3-based sorted insert (5 ops vs 9), explicit 2-deep load rotation.
// 16-way scan split x 4 query groups; 16 queries/wave; 512 blocks x 4 waves.

#define NB     8
#define NPTS   4096
#define INV_H2 1111.1111111111111f   // 1 / (0.03*0.03)
#define BIG    1e30f

__device__ __forceinline__ float med3(float a, float b, float c) {
#if __has_builtin(__builtin_amdgcn_fmed3f)
    return __builtin_amdgcn_fmed3f(a, b, c);
#else
    return fminf(b, fmaxf(a, c));   // valid under precondition a <= b
#endif
}

// branchless insert of e into sorted ascending d[K][0..4]
// d_i' = med3(d_{i-1}, d_i, e) (sorted precondition), d_0' = min(d_0, e)
#define INS5(K, e)                              \
    do {                                        \
        d[K][4] = med3(d[K][3], d[K][4], (e));  \
        d[K][3] = med3(d[K][2], d[K][3], (e));  \
        d[K][2] = med3(d[K][1], d[K][2], (e));  \
        d[K][1] = med3(d[K][0], d[K][1], (e));  \
        d[K][0] = fminf(d[K][0], (e));          \
    } while (0)

// process one point v against the lane's 4 queries (shifted dist |p|^2 - 2 p.q)
#define PROC1(K, v)                                      \
    do {                                                 \
        float _a = fmaf((v).x, nqx[K], (v).w);           \
        _a = fmaf((v).y, nqy[K], _a);                    \
        _a = fmaf((v).z, nqz[K], _a);                    \
        INS5(K, _a);                                     \
    } while (0)

#define PROC(v) do { PROC1(0, v); PROC1(1, v); PROC1(2, v); PROC1(3, v); } while (0)

// ---------------- prep: (x,y,z) -> (x,y,z,|p|^2) ------------------------------
__global__ __launch_bounds__(256) void prep_kernel(const float* __restrict__ pc,
                                                   float4* __restrict__ pts4) {
    int i = blockIdx.x * 256 + threadIdx.x;
    if (i < NB * NPTS) {
        float x = pc[3 * i + 0];
        float y = pc[3 * i + 1];
        float z = pc[3 * i + 2];
        float n = fmaf(x, x, fmaf(y, y, z * z));
        pts4[i] = make_float4(x, y, z, n);
    }
}

// ---------------- main: Q=4 per lane, 16-way split, butterfly merge ------------
// block = 256 = 4 waves; wave = 4 qg x 16 s; each lane owns 4 queries.
// 64 queries per block; grid = 32768/64 = 512 blocks (2 per CU).
__global__ __launch_bounds__(256, 2) void knn_kernel(const float4* __restrict__ pts4,
                                                     float* __restrict__ partials) {
    const int tid  = threadIdx.x;
    const int lane = tid & 63;
    const int wid  = tid >> 6;
    const int qg   = lane >> 4;   // query group: 0..3
    const int s    = lane & 15;   // scan subset: 0..15

    const int b   = blockIdx.x >> 6;            // 64 blocks per batch
    const int iq0 = ((blockIdx.x & 63) << 6) + (wid << 4) + (qg << 2);

    const float4* __restrict__ base = pts4 + b * NPTS;

    float nqx[4], nqy[4], nqz[4], Cq[4];
    #pragma unroll
    for (int k = 0; k < 4; ++k) {
        float4 qk = base[iq0 + k];
        nqx[k] = -2.0f * qk.x;
        nqy[k] = -2.0f * qk.y;
        nqz[k] = -2.0f * qk.z;
        Cq[k]  = qk.w;            // |q|^2, re-added after merge
    }

    // sorted ascending top-5 of SHIFTED distance |p|^2 - 2 p.q per query
    // (self == -|q|^2 is the exact minimum -> lands in d[k][0], dropped)
    float d[4][5];
    #pragma unroll
    for (int k = 0; k < 4; ++k)
        #pragma unroll
        for (int j = 0; j < 5; ++j) d[k][j] = BIG;

    // lane s scans j == s (mod 16): 256 points, 2 per trip, next pair prefetched
    const float4* __restrict__ p = base + s;
    float4 va = p[0];
    float4 vb = p[16];
    p += 32;
    for (int t = 0; t < NPTS / 32 - 1; ++t) {   // 127 trips + tail
        float4 vc = p[0];
        float4 vd = p[16];
        p += 32;
        PROC(va);
        PROC(vb);
        va = vc;
        vb = vd;
    }
    PROC(va);
    PROC(vb);

    // merge the 16 subsets' sorted top-5 lists (xor butterfly over s bits)
    #pragma unroll
    for (int m = 1; m <= 8; m <<= 1) {
        #pragma unroll
        for (int k = 0; k < 4; ++k) {
            float e0 = __shfl_xor(d[k][0], m);
            float e1 = __shfl_xor(d[k][1], m);
            float e2 = __shfl_xor(d[k][2], m);
            float e3 = __shfl_xor(d[k][3], m);
            float e4 = __shfl_xor(d[k][4], m);
            INS5(k, e0);
            INS5(k, e1);
            INS5(k, e2);
            INS5(k, e3);
            INS5(k, e4);
        }
    }

    // d[k][0] == self; d[k][1..4] + Cq[k] are the 4 true NN squared distances.
    float lsum = 0.0f;
    if (s == 0) {
        #pragma unroll
        for (int k = 0; k < 4; ++k) {
            #pragma unroll
            for (int j = 1; j < 5; ++j) {
                float e = fmaxf(d[k][j] + Cq[k], 0.0f);
                lsum = fmaf(e, __expf(-e * INV_H2), lsum);
            }
        }
        lsum = -lsum;
    }

    // wave reduce (lanes with s!=0 hold 0)
    #pragma unroll
    for (int m = 32; m >= 1; m >>= 1) lsum += __shfl_xor(lsum, m);

    __shared__ float wsum[4];
    if (lane == 0) wsum[wid] = lsum;
    __syncthreads();
    if (tid == 0) partials[blockIdx.x] = wsum[0] + wsum[1] + wsum[2] + wsum[3];
}

// ---------------- final reduction of 512 block partials ------------------------
__global__ __launch_bounds__(256) void reduce_kernel(const float* __restrict__ partials,
                                                     float* __restrict__ out) {
    int tid = threadIdx.x;
    float v = partials[tid] + partials[tid + 256];
    #pragma unroll
    for (int m = 32; m >= 1; m >>= 1) v += __shfl_xor(v, m);
    __shared__ float ws[4];
    if ((tid & 63) == 0) ws[tid >> 6] = v;
    __syncthreads();
    if (tid == 0) out[0] = ws[0] + ws[1] + ws[2] + ws[3];
}

extern "C" void kernel_launch(void* const* d_in, const int* in_sizes, int n_in,
                              void* d_out, int out_size, void* d_ws, size_t ws_size,
                              hipStream_t stream) {
    const float* pc = (const float*)d_in[0];
    float* out = (float*)d_out;

    float4* pts4    = (float4*)d_ws;
    float* partials = (float*)((char*)d_ws + (size_t)NB * NPTS * sizeof(float4));

    prep_kernel<<<(NB * NPTS + 255) / 256, 256, 0, stream>>>(pc, pts4);
    knn_kernel<<<NB * NPTS / 64, 256, 0, stream>>>(pts4, partials);
    reduce_kernel<<<1, 256, 0, stream>>>(partials, out);
}

// Round 6
// 84.570 us; speedup vs baseline: 1.4282x; 1.1165x over previous
//
#include <hip/hip_runtime.h>
#include <math.h>

// RepulsionLoss: B=8, N=4096, 3D points, k=4 NN (skip self), H=0.03
// loss = sum_q sum_{4NN} -d * exp(-d / H^2)
//
// Round-6: ONE fused kernel.
//  - Batch's 4096 points staged to LDS (64KB exactly) as (x,y,z,|p|^2);
//    raw float3 input read via coalesced float4 loads, norm computed in-flight
//    (prep kernel eliminated).
//  - Scan from LDS with explicit 4-float4 ping-pong pipeline (ds_read_b128
//    with immediate offsets; one pointer bump per 8 points).
//  - Q=4 queries/lane (register tiling), med3 sorted-insert (5 ops),
//    shifted distance |p|^2 - 2 p.q (3 fma), self = exact min -> dropped.
//  - Block partial -> one atomicAdd per block (reduce kernel eliminated);
//    d_out zeroed via hipMemsetAsync.

#define NB     8
#define NPTS   4096
#define INV_H2 1111.1111111111111f   // 1 / (0.03*0.03)
#define BIG    1e30f

__device__ __forceinline__ float med3(float a, float b, float c) {
#if __has_builtin(__builtin_amdgcn_fmed3f)
    return __builtin_amdgcn_fmed3f(a, b, c);
#else
    return fminf(b, fmaxf(a, c));   // valid under precondition a <= b
#endif
}

// branchless insert of e into sorted ascending d[K][0..4]
#define INS5(K, e)                              \
    do {                                        \
        d[K][4] = med3(d[K][3], d[K][4], (e));  \
        d[K][3] = med3(d[K][2], d[K][3], (e));  \
        d[K][2] = med3(d[K][1], d[K][2], (e));  \
        d[K][1] = med3(d[K][0], d[K][1], (e));  \
        d[K][0] = fminf(d[K][0], (e));          \
    } while (0)

// one point v against the lane's 4 queries (shifted dist |p|^2 - 2 p.q)
#define PROC1(K, v)                              \
    do {                                         \
        float _a = fmaf((v).x, nqx[K], (v).w);   \
        _a = fmaf((v).y, nqy[K], _a);            \
        _a = fmaf((v).z, nqz[K], _a);            \
        INS5(K, _a);                             \
    } while (0)

#define PROC(v) do { PROC1(0, v); PROC1(1, v); PROC1(2, v); PROC1(3, v); } while (0)

// block = 256 threads = 4 waves; wave = 4 query-groups x 16 scan-lanes,
// Q=4 queries per lane -> 64 queries/block; grid = 32768/64 = 512 blocks
// (2 blocks/CU, LDS-bound at 64KB).
__global__ __launch_bounds__(256, 2) void knn_kernel(const float* __restrict__ pc,
                                                     float* __restrict__ out) {
    __shared__ float4 lds4[NPTS];   // exactly 64 KiB

    const int tid  = threadIdx.x;
    const int lane = tid & 63;
    const int wid  = tid >> 6;
    const int qg   = lane >> 4;   // query group: 0..3
    const int s    = lane & 15;   // scan subset: 0..15

    const int b   = blockIdx.x >> 6;            // 64 blocks per batch
    const int iq0 = ((blockIdx.x & 63) << 6) + (wid << 4) + (qg << 2);

    // ---- stage: 4096 raw points -> LDS as (x,y,z,|p|^2) -----------------------
    // thread t, pass p: points p*1024 + 4t .. +3, read as 3 coalesced float4.
    const float4* __restrict__ gp = (const float4*)pc + b * 3072;
    #pragma unroll
    for (int p = 0; p < 4; ++p) {
        int t3 = p * 768 + tid * 3;
        float4 f0 = gp[t3 + 0];
        float4 f1 = gp[t3 + 1];
        float4 f2 = gp[t3 + 2];
        int j0 = p * 1024 + tid * 4;
        float n0 = fmaf(f0.x, f0.x, fmaf(f0.y, f0.y, f0.z * f0.z));
        float n1 = fmaf(f0.w, f0.w, fmaf(f1.x, f1.x, f1.y * f1.y));
        float n2 = fmaf(f1.z, f1.z, fmaf(f1.w, f1.w, f2.x * f2.x));
        float n3 = fmaf(f2.y, f2.y, fmaf(f2.z, f2.z, f2.w * f2.w));
        lds4[j0 + 0] = make_float4(f0.x, f0.y, f0.z, n0);
        lds4[j0 + 1] = make_float4(f0.w, f1.x, f1.y, n1);
        lds4[j0 + 2] = make_float4(f1.z, f1.w, f2.x, n2);
        lds4[j0 + 3] = make_float4(f2.y, f2.z, f2.w, n3);
    }
    __syncthreads();

    // ---- per-lane query setup ------------------------------------------------
    float nqx[4], nqy[4], nqz[4], Cq[4];
    #pragma unroll
    for (int k = 0; k < 4; ++k) {
        float4 qk = lds4[iq0 + k];
        nqx[k] = -2.0f * qk.x;
        nqy[k] = -2.0f * qk.y;
        nqz[k] = -2.0f * qk.z;
        Cq[k]  = qk.w;            // |q|^2, re-added after merge
    }

    // sorted ascending top-5 of SHIFTED distance (self == -|q|^2 == exact min)
    float d[4][5];
    #pragma unroll
    for (int k = 0; k < 4; ++k)
        #pragma unroll
        for (int j = 0; j < 5; ++j) d[k][j] = BIG;

    // ---- scan: lane handles points s+16m, m=0..255; ping-pong 4-float4 -------
    const float4* lp = &lds4[s];
    float4 P0 = lp[0],  P1 = lp[16], P2 = lp[32], P3 = lp[48];
    float4 Q0, Q1, Q2, Q3;
    for (int i = 0; i < 31; ++i) {
        Q0 = lp[64]; Q1 = lp[80]; Q2 = lp[96]; Q3 = lp[112];
        PROC(P0); PROC(P1); PROC(P2); PROC(P3);
        lp += 128;
        P0 = lp[0]; P1 = lp[16]; P2 = lp[32]; P3 = lp[48];
        PROC(Q0); PROC(Q1); PROC(Q2); PROC(Q3);
    }
    Q0 = lp[64]; Q1 = lp[80]; Q2 = lp[96]; Q3 = lp[112];
    PROC(P0); PROC(P1); PROC(P2); PROC(P3);
    PROC(Q0); PROC(Q1); PROC(Q2); PROC(Q3);

    // ---- merge the 16 subsets (xor butterfly over s bits) --------------------
    #pragma unroll
    for (int m = 1; m <= 8; m <<= 1) {
        #pragma unroll
        for (int k = 0; k < 4; ++k) {
            float e0 = __shfl_xor(d[k][0], m);
            float e1 = __shfl_xor(d[k][1], m);
            float e2 = __shfl_xor(d[k][2], m);
            float e3 = __shfl_xor(d[k][3], m);
            float e4 = __shfl_xor(d[k][4], m);
            INS5(k, e0);
            INS5(k, e1);
            INS5(k, e2);
            INS5(k, e3);
            INS5(k, e4);
        }
    }

    // ---- loss: d[k][0]==self; d[k][1..4]+Cq are the 4 NN squared dists -------
    float lsum = 0.0f;
    if (s == 0) {
        #pragma unroll
        for (int k = 0; k < 4; ++k) {
            #pragma unroll
            for (int j = 1; j < 5; ++j) {
                float e = fmaxf(d[k][j] + Cq[k], 0.0f);
                lsum = fmaf(e, __expf(-e * INV_H2), lsum);
            }
        }
        lsum = -lsum;
    }

    // wave reduce (lanes with s!=0 hold 0; qg lanes hold distinct queries)
    #pragma unroll
    for (int m = 32; m >= 1; m >>= 1) lsum += __shfl_xor(lsum, m);

    // block reduce via lds4 reuse (all waves done scanning first), one atomic
    __syncthreads();
    float* ws = (float*)lds4;
    if (lane == 0) ws[wid] = lsum;
    __syncthreads();
    if (tid == 0) atomicAdd(out, ws[0] + ws[1] + ws[2] + ws[3]);
}

extern "C" void kernel_launch(void* const* d_in, const int* in_sizes, int n_in,
                              void* d_out, int out_size, void* d_ws, size_t ws_size,
                              hipStream_t stream) {
    const float* pc = (const float*)d_in[0];
    float* out = (float*)d_out;

    hipMemsetAsync(out, 0, sizeof(float), stream);   // d_out is poisoned 0xAA
    knn_kernel<<<NB * NPTS / 64, 256, 0, stream>>>(pc, out);
}